// Round 6
// baseline (400.316 us; speedup 1.0000x reference)
//
#include <hip/hip_runtime.h>
#include <hip/hip_bf16.h>

#define HD 128
#define NBA 256        // max buckets (node >> 8); array stride
#define LEAKY 0.2f
#define LN_EPS 1e-5f

// ---- bf16 helpers (manual, RNE) ----
__device__ __forceinline__ unsigned short bfr(float f) {
    unsigned int b = __float_as_uint(f);
    return (unsigned short)((b + 0x7fffu + ((b >> 16) & 1u)) >> 16);
}
__device__ __forceinline__ float blo(unsigned int u) { return __uint_as_float(u << 16); }
__device__ __forceinline__ float bhi(unsigned int u) { return __uint_as_float(u & 0xffff0000u); }

// ---------- k1: fp32 -> bf16 conversion (ego) + zero degree arrays ----------
__global__ __launch_bounds__(256) void conv_zero(
    const float* __restrict__ x, unsigned short* __restrict__ y, int n4,
    int* __restrict__ deg, int ndeg) {
    int stride = gridDim.x * 256;
    for (int i = blockIdx.x * 256 + threadIdx.x; i < n4; i += stride) {
        float4 f = ((const float4*)x)[i];
        ushort4 u;
        u.x = bfr(f.x); u.y = bfr(f.y); u.z = bfr(f.z); u.w = bfr(f.w);
        ((ushort4*)y)[i] = u;
    }
    for (int i = blockIdx.x * 256 + threadIdx.x; i < ndeg; i += stride)
        deg[i] = 0;
}

// ---------- k2: per-node degree counts (both directions) ----------
// 1.6M device-scope atomics over 100k counters (~16 hits each): contention
// is negligible; runs at near-store throughput. Replaces the old two-level
// LDS-histogram partition entirely.
__global__ __launch_bounds__(256) void count_deg(
    const int* __restrict__ rows, const int* __restrict__ cols,
    int* __restrict__ deg_r, int* __restrict__ deg_c, int nnz) {
    int stride = gridDim.x * 256;
    int t = blockIdx.x * 256 + threadIdx.x;
    int n4 = nnz >> 2;
    for (int j = t; j < n4; j += stride) {
        int4 r = ((const int4*)rows)[j];
        int4 c = ((const int4*)cols)[j];
        atomicAdd(&deg_r[r.x], 1); atomicAdd(&deg_r[r.y], 1);
        atomicAdd(&deg_r[r.z], 1); atomicAdd(&deg_r[r.w], 1);
        atomicAdd(&deg_c[c.x], 1); atomicAdd(&deg_c[c.y], 1);
        atomicAdd(&deg_c[c.z], 1); atomicAdd(&deg_c[c.w], 1);
    }
    for (int j = (n4 << 2) + t; j < nnz; j += stride) {
        atomicAdd(&deg_r[rows[j]], 1);
        atomicAdd(&deg_c[cols[j]], 1);
    }
}

// ---------- k3: per-bucket local exclusive scan of degrees ----------
// grid (NBK, 2), 256 threads = 256-node bucket. Writes local (base-less)
// exclusive scan into rp and the bucket total.
__global__ __launch_bounds__(256) void bucket_sums(
    const int* __restrict__ deg_r, const int* __restrict__ deg_c,
    int* __restrict__ rp_r, int* __restrict__ rp_c,
    int* __restrict__ totals, int n) {
    __shared__ int wsum[4];
    int bkt = blockIdx.x, dir = blockIdx.y, tid = threadIdx.x;
    const int* deg = dir ? deg_c : deg_r;
    int* rp = dir ? rp_c : rp_r;
    int g = (bkt << 8) + tid;
    int v = (g < n) ? deg[g] : 0;
    int lane = tid & 63, wid = tid >> 6;
    int incl = v;
    #pragma unroll
    for (int off = 1; off < 64; off <<= 1) {
        int t = __shfl_up(incl, off);
        if (lane >= off) incl += t;
    }
    if (lane == 63) wsum[wid] = incl;
    __syncthreads();
    int wbase = 0;
    #pragma unroll
    for (int w = 0; w < 4; ++w) if (w < wid) wbase += wsum[w];
    int excl = wbase + incl - v;
    if (g < n) rp[g] = excl;
    if (tid == 255) totals[dir * NBA + bkt] = wbase + incl;
}

// ---------- k4: bucket bases (exclusive scan of up to 256 totals/dir) ------
__global__ __launch_bounds__(128) void base_scan(
    const int* __restrict__ totals, int* __restrict__ bases,
    int* __restrict__ rp_r, int* __restrict__ rp_c, int nbk, int n, int nnz) {
    int dir = threadIdx.x >> 6, lane = threadIdx.x & 63;
    int v[4], s = 0;
    #pragma unroll
    for (int j = 0; j < 4; ++j) {
        int b = lane * 4 + j;
        v[j] = (b < nbk) ? totals[dir * NBA + b] : 0;
        s += v[j];
    }
    int incl = s;
    #pragma unroll
    for (int off = 1; off < 64; off <<= 1) {
        int t = __shfl_up(incl, off);
        if (lane >= off) incl += t;
    }
    int excl = incl - s;
    #pragma unroll
    for (int j = 0; j < 4; ++j) {
        bases[dir * NBA + lane * 4 + j] = excl;
        excl += v[j];
    }
    if (lane == 0) (dir ? rp_c : rp_r)[n] = nnz;
}

// ---------- k5: finalize rp (+base) and init write cursors ----------
__global__ __launch_bounds__(256) void add_base(
    const int* __restrict__ bases,
    int* __restrict__ rp_r, int* __restrict__ rp_c,
    int* __restrict__ cur_r, int* __restrict__ cur_c, int n) {
    int bkt = blockIdx.x, dir = blockIdx.y, tid = threadIdx.x;
    int g = (bkt << 8) + tid;
    if (g >= n) return;
    int* rp = dir ? rp_c : rp_r;
    int* cur = dir ? cur_c : cur_r;
    int v = rp[g] + bases[dir * NBA + bkt];
    rp[g] = v;
    cur[g] = v;
}

// ---------- k6: direct scatter into final CSR entry arrays ----------
// pos = atomicAdd(cursor[node]); ent[pos] = other | bf16(val)<<16.
// Within-row edge order is nondeterministic (sum order permutes; well
// inside tolerance). No staging buffers, no second pass.
__global__ __launch_bounds__(256) void scatter_direct(
    const int* __restrict__ rows, const int* __restrict__ cols,
    const float* __restrict__ vals,
    int* __restrict__ cur_r, int* __restrict__ cur_c,
    unsigned* __restrict__ ent_r, unsigned* __restrict__ ent_c, int nnz) {
    int stride = gridDim.x * 256;
    for (int i = blockIdx.x * 256 + threadIdx.x; i < nnz; i += stride) {
        int ro = rows[i], co = cols[i];
        unsigned vb = (unsigned)bfr(vals[i]) << 16;
        int pr = atomicAdd(&cur_r[ro], 1);
        ent_r[pr] = vb | (unsigned)co;
        int pc = atomicAdd(&cur_c[co], 1);
        ent_c[pc] = vb | (unsigned)ro;
    }
}

// ---------- bf16-gather SpMM (+ optional fused leaky/LN/residual) ----------
// One wave per output row. Quarter-wave (16 lanes) x 16 B (8 bf16) covers a
// 256 B row; the 4 quarters process interleaved edges. The edge loop is
// fully predicated 4-wide: every quarter always has 4 independent gathers in
// flight regardless of degree (padded edges are clamped to end-1 and their
// value forced to 0 -> contribute exactly 0).
// Entry decode: val = bhi(e), src = e & 0xffff.
// post: 0 = none (bf16 out), 1 = leaky+LN+res (bf16 out), 2 = LN+res (fp32 out).
__global__ __launch_bounds__(256) void spmm_bf(
    const unsigned short* __restrict__ x, const int* __restrict__ rp,
    const unsigned* __restrict__ ent,
    const float* __restrict__ res, const float* __restrict__ gamma,
    const float* __restrict__ beta,
    unsigned short* __restrict__ out_bf, float* __restrict__ out_f32,
    int n, int post) {
    int wid = threadIdx.x >> 6, lane = threadIdx.x & 63;
    int row = blockIdx.x * 4 + wid;
    if (row >= n) return;
    int quarter = lane >> 4, q = lane & 15;
    int beg = rp[row], end = rp[row + 1];
    float acc[8];
    #pragma unroll
    for (int k = 0; k < 8; ++k) acc[k] = 0.f;

    int last = end - 1;
    for (int i0 = beg + quarter; i0 < end; i0 += 16) {
        int i1 = i0 + 4, i2 = i0 + 8, i3 = i0 + 12;
        unsigned e0 = ent[i0];
        unsigned e1 = ent[i1 < end ? i1 : last];
        unsigned e2 = ent[i2 < end ? i2 : last];
        unsigned e3 = ent[i3 < end ? i3 : last];
        uint4 u0 = ((const uint4*)(x + (size_t)(e0 & 0xffffu) * HD))[q];
        uint4 u1 = ((const uint4*)(x + (size_t)(e1 & 0xffffu) * HD))[q];
        uint4 u2 = ((const uint4*)(x + (size_t)(e2 & 0xffffu) * HD))[q];
        uint4 u3 = ((const uint4*)(x + (size_t)(e3 & 0xffffu) * HD))[q];
        float v0 = bhi(e0);
        float v1 = i1 < end ? bhi(e1) : 0.f;
        float v2 = i2 < end ? bhi(e2) : 0.f;
        float v3 = i3 < end ? bhi(e3) : 0.f;
        acc[0] += v0 * blo(u0.x) + v1 * blo(u1.x);
        acc[1] += v0 * bhi(u0.x) + v1 * bhi(u1.x);
        acc[2] += v0 * blo(u0.y) + v1 * blo(u1.y);
        acc[3] += v0 * bhi(u0.y) + v1 * bhi(u1.y);
        acc[4] += v0 * blo(u0.z) + v1 * blo(u1.z);
        acc[5] += v0 * bhi(u0.z) + v1 * bhi(u1.z);
        acc[6] += v0 * blo(u0.w) + v1 * blo(u1.w);
        acc[7] += v0 * bhi(u0.w) + v1 * bhi(u1.w);
        acc[0] += v2 * blo(u2.x) + v3 * blo(u3.x);
        acc[1] += v2 * bhi(u2.x) + v3 * bhi(u3.x);
        acc[2] += v2 * blo(u2.y) + v3 * blo(u3.y);
        acc[3] += v2 * bhi(u2.y) + v3 * bhi(u3.y);
        acc[4] += v2 * blo(u2.z) + v3 * blo(u3.z);
        acc[5] += v2 * bhi(u2.z) + v3 * bhi(u3.z);
        acc[6] += v2 * blo(u2.w) + v3 * blo(u3.w);
        acc[7] += v2 * bhi(u2.w) + v3 * bhi(u3.w);
    }
    // combine the 4 quarters
    #pragma unroll
    for (int k = 0; k < 8; ++k) {
        acc[k] += __shfl_xor(acc[k], 16);
        acc[k] += __shfl_xor(acc[k], 32);
    }
    if (quarter != 0) return;

    if (post == 0) {
        uint4 s;
        s.x = (unsigned)bfr(acc[0]) | ((unsigned)bfr(acc[1]) << 16);
        s.y = (unsigned)bfr(acc[2]) | ((unsigned)bfr(acc[3]) << 16);
        s.z = (unsigned)bfr(acc[4]) | ((unsigned)bfr(acc[5]) << 16);
        s.w = (unsigned)bfr(acc[6]) | ((unsigned)bfr(acc[7]) << 16);
        ((uint4*)(out_bf + (size_t)row * HD))[q] = s;
        return;
    }
    if (post == 1) {
        #pragma unroll
        for (int k = 0; k < 8; ++k) acc[k] = acc[k] >= 0.f ? acc[k] : LEAKY * acc[k];
    }
    float t = 0.f;
    #pragma unroll
    for (int k = 0; k < 8; ++k) t += acc[k];
    #pragma unroll
    for (int off = 1; off < 16; off <<= 1) t += __shfl_xor(t, off);
    float mu = t * (1.f / HD);
    float d[8], vs = 0.f;
    #pragma unroll
    for (int k = 0; k < 8; ++k) { d[k] = acc[k] - mu; vs += d[k] * d[k]; }
    #pragma unroll
    for (int off = 1; off < 16; off <<= 1) vs += __shfl_xor(vs, off);
    float inv = rsqrtf(vs * (1.f / HD) + LN_EPS);

    float4 g0 = ((const float4*)gamma)[2 * q], g1 = ((const float4*)gamma)[2 * q + 1];
    float4 b0 = ((const float4*)beta)[2 * q],  b1 = ((const float4*)beta)[2 * q + 1];
    float4 r0 = ((const float4*)(res + (size_t)row * HD))[2 * q];
    float4 r1 = ((const float4*)(res + (size_t)row * HD))[2 * q + 1];
    float o[8];
    o[0] = d[0] * inv * g0.x + b0.x + r0.x;
    o[1] = d[1] * inv * g0.y + b0.y + r0.y;
    o[2] = d[2] * inv * g0.z + b0.z + r0.z;
    o[3] = d[3] * inv * g0.w + b0.w + r0.w;
    o[4] = d[4] * inv * g1.x + b1.x + r1.x;
    o[5] = d[5] * inv * g1.y + b1.y + r1.y;
    o[6] = d[6] * inv * g1.z + b1.z + r1.z;
    o[7] = d[7] * inv * g1.w + b1.w + r1.w;
    if (post == 1) {
        uint4 s;
        s.x = (unsigned)bfr(o[0]) | ((unsigned)bfr(o[1]) << 16);
        s.y = (unsigned)bfr(o[2]) | ((unsigned)bfr(o[3]) << 16);
        s.z = (unsigned)bfr(o[4]) | ((unsigned)bfr(o[5]) << 16);
        s.w = (unsigned)bfr(o[6]) | ((unsigned)bfr(o[7]) << 16);
        ((uint4*)(out_bf + (size_t)row * HD))[q] = s;
    } else {
        float4 s0 = {o[0], o[1], o[2], o[3]};
        float4 s1 = {o[4], o[5], o[6], o[7]};
        ((float4*)(out_f32 + (size_t)row * HD))[2 * q] = s0;
        ((float4*)(out_f32 + (size_t)row * HD))[2 * q + 1] = s1;
    }
}

extern "C" void kernel_launch(void* const* d_in, const int* in_sizes, int n_in,
                              void* d_out, int out_size, void* d_ws, size_t ws_size,
                              hipStream_t stream) {
    const float* ego   = (const float*)d_in[0];
    const float* vals  = (const float*)d_in[1];
    const float* gamma = (const float*)d_in[2];
    const float* beta  = (const float*)d_in[3];
    const int*   rows  = (const int*)d_in[4];
    const int*   cols  = (const int*)d_in[5];

    const int N   = in_sizes[0] / HD;   // 50000 (< 65536 for 16-bit node ids)
    const int NNZ = in_sizes[1];        // 800000
    const int NBK = (N + 255) >> 8;     // 196 buckets (<= 256)

    float* out = (float*)d_out;
    char* w = (char*)d_ws;
    unsigned short* ego_bf = (unsigned short*)w; w += (size_t)N * HD * 2;
    unsigned short* bufA   = (unsigned short*)w; w += (size_t)N * HD * 2;
    unsigned short* bufB   = (unsigned short*)w; w += (size_t)N * HD * 2;
    int*  rp_r = (int*)w;  w += (size_t)(N + 4) * 4;
    int*  rp_c = (int*)w;  w += (size_t)(N + 4) * 4;
    unsigned* ent_r = (unsigned*)w; w += (size_t)NNZ * 4;
    unsigned* ent_c = (unsigned*)w; w += (size_t)NNZ * 4;
    int* deg_r = (int*)w;  w += (size_t)N * 4;   // deg_r, deg_c contiguous
    int* deg_c = (int*)w;  w += (size_t)N * 4;
    int* cur_r = (int*)w;  w += (size_t)N * 4;
    int* cur_c = (int*)w;  w += (size_t)N * 4;
    int* totals = (int*)w; w += (size_t)2 * NBA * 4;
    int* bases  = (int*)w; w += (size_t)2 * NBA * 4;

    // ---- build both CSRs + bf16 ego (direct counting sort, no staging) ----
    conv_zero<<<2048, 256, 0, stream>>>(ego, ego_bf, N * HD / 4, deg_r, 2 * N);
    count_deg<<<1024, 256, 0, stream>>>(rows, cols, deg_r, deg_c, NNZ);
    bucket_sums<<<dim3(NBK, 2), 256, 0, stream>>>(deg_r, deg_c, rp_r, rp_c,
                                                  totals, N);
    base_scan<<<1, 128, 0, stream>>>(totals, bases, rp_r, rp_c, NBK, N, NNZ);
    add_base<<<dim3(NBK, 2), 256, 0, stream>>>(bases, rp_r, rp_c, cur_r, cur_c, N);
    scatter_direct<<<1024, 256, 0, stream>>>(rows, cols, vals, cur_r, cur_c,
                                             ent_r, ent_c, NNZ);

    const int sblocks = (N + 3) / 4;

    // ---- layer 0 ----
    spmm_bf<<<sblocks, 256, 0, stream>>>(ego_bf, rp_c, ent_c,
                                         nullptr, nullptr, nullptr, bufA, nullptr, N, 0);
    spmm_bf<<<sblocks, 256, 0, stream>>>(bufA, rp_r, ent_r,
                                         ego, gamma, beta, bufB, nullptr, N, 1);
    // ---- layer 1 ----
    spmm_bf<<<sblocks, 256, 0, stream>>>(bufB, rp_c, ent_c,
                                         nullptr, nullptr, nullptr, bufA, nullptr, N, 0);
    spmm_bf<<<sblocks, 256, 0, stream>>>(bufA, rp_r, ent_r,
                                         ego, gamma + HD, beta + HD, nullptr, out, N, 2);
}

// Round 8
// 305.910 us; speedup vs baseline: 1.3086x; 1.3086x over previous
//
#include <hip/hip_runtime.h>
#include <hip/hip_bf16.h>

#define HD 128
#define PB 256         // partition blocks
#define NBA 256        // max buckets (node >> 8); array stride
#define LEAKY 0.2f
#define LN_EPS 1e-5f

// ---- bf16 helpers (manual, RNE) ----
__device__ __forceinline__ unsigned short bfr(float f) {
    unsigned int b = __float_as_uint(f);
    return (unsigned short)((b + 0x7fffu + ((b >> 16) & 1u)) >> 16);
}
__device__ __forceinline__ float blo(unsigned int u) { return __uint_as_float(u << 16); }
__device__ __forceinline__ float bhi(unsigned int u) { return __uint_as_float(u & 0xffff0000u); }

// ---------- k1: fp32 -> bf16 conversion (ego) + zero per-node degree ----------
__global__ __launch_bounds__(256) void conv_zero(
    const float* __restrict__ x, unsigned short* __restrict__ y, int n4,
    int* __restrict__ deg, int ndeg) {
    int stride = gridDim.x * 256;
    for (int i = blockIdx.x * 256 + threadIdx.x; i < n4; i += stride) {
        float4 f = ((const float4*)x)[i];
        ushort4 u;
        u.x = bfr(f.x); u.y = bfr(f.y); u.z = bfr(f.z); u.w = bfr(f.w);
        ((ushort4*)y)[i] = u;
    }
    for (int i = blockIdx.x * 256 + threadIdx.x; i < ndeg; i += stride)
        deg[i] = 0;
}

// ---------- k2: per-block bucket counts + fused per-node degree counts ------
// LDS histogram per 256-node bucket (for the partition offsets) + global
// per-node atomics (1.6M over 100k counters -> lines aggregate in L2; round-6
// measured this pattern <43us standalone, amortized here behind the same
// rows/cols reads). deg eliminates bucket_build's counting pass entirely.
__global__ __launch_bounds__(256) void part_count(
    const int* __restrict__ rows, const int* __restrict__ cols,
    int* __restrict__ counts, int* __restrict__ deg_r, int* __restrict__ deg_c,
    int nnz) {
    __shared__ int cR[NBA], cC[NBA];
    cR[threadIdx.x] = 0; cC[threadIdx.x] = 0;
    __syncthreads();
    int chunk = (nnz + PB - 1) / PB;
    int beg = blockIdx.x * chunk;
    int end = min(beg + chunk, nnz);
    for (int i = beg + threadIdx.x; i < end; i += 256) {
        int ro = rows[i], co = cols[i];
        atomicAdd(&cR[ro >> 8], 1);
        atomicAdd(&cC[co >> 8], 1);
        atomicAdd(&deg_r[ro], 1);
        atomicAdd(&deg_c[co], 1);
    }
    __syncthreads();
    counts[(size_t)blockIdx.x * NBA + threadIdx.x] = cR[threadIdx.x];
    counts[(size_t)PB * NBA + (size_t)blockIdx.x * NBA + threadIdx.x] = cC[threadIdx.x];
}

// k2a: for each (dir,bucket), exclusive scan over PB block counts (in-place
// counts -> offsets), emit totals[dir*NBA+bkt]. One wave per block.
__global__ __launch_bounds__(64) void part_off(
    int* __restrict__ counts, int* __restrict__ totals) {
    int bkt = blockIdx.x, dir = blockIdx.y, lane = threadIdx.x;
    int* p = counts + (size_t)dir * PB * NBA;
    int v[4], s = 0;
    #pragma unroll
    for (int j = 0; j < 4; ++j) {
        int blk = lane * 4 + j;
        v[j] = p[(size_t)blk * NBA + bkt];
        s += v[j];
    }
    int incl = s;
    #pragma unroll
    for (int off = 1; off < 64; off <<= 1) {
        int t = __shfl_up(incl, off);
        if (lane >= off) incl += t;
    }
    int excl = incl - s;
    #pragma unroll
    for (int j = 0; j < 4; ++j) {
        int blk = lane * 4 + j;
        p[(size_t)blk * NBA + bkt] = excl;
        excl += v[j];
    }
    if (lane == 63) totals[dir * NBA + bkt] = incl;
}

// k2b: bucket bases (exclusive scan of up to 256 totals per dir; one wave per
// dir, 4 buckets per lane), plus rp[N] = nnz.
__global__ __launch_bounds__(128) void base_scan(
    const int* __restrict__ totals, int* __restrict__ bases,
    int* __restrict__ rp_r, int* __restrict__ rp_c, int nbk, int n, int nnz) {
    int dir = threadIdx.x >> 6, lane = threadIdx.x & 63;
    int v[4], s = 0;
    #pragma unroll
    for (int j = 0; j < 4; ++j) {
        int b = lane * 4 + j;
        v[j] = (b < nbk) ? totals[dir * NBA + b] : 0;
        s += v[j];
    }
    int incl = s;
    #pragma unroll
    for (int off = 1; off < 64; off <<= 1) {
        int t = __shfl_up(incl, off);
        if (lane >= off) incl += t;
    }
    int excl = incl - s;
    #pragma unroll
    for (int j = 0; j < 4; ++j) {
        bases[dir * NBA + lane * 4 + j] = excl;
        excl += v[j];
    }
    if (lane == 0) (dir ? rp_c : rp_r)[n] = nnz;
}

// k3: scatter edges into bucket-major staging: stg[dir] entry = (payload, bin),
// payload = other | (bf16(val) << 16). Per-(block,bucket) destination ranges
// are contiguous -> block-exclusive line assembly (no cross-XCD line sharing,
// no write amplification -- the round-6 lesson).
__global__ __launch_bounds__(256) void part_scatter(
    const int* __restrict__ rows, const int* __restrict__ cols,
    const float* __restrict__ vals,
    const int* __restrict__ counts, const int* __restrict__ bases,
    uint2* __restrict__ stg_r, uint2* __restrict__ stg_c, int nnz) {
    __shared__ int cR[NBA], cC[NBA], wbR[NBA], wbC[NBA];
    int t = threadIdx.x;
    cR[t] = 0; cC[t] = 0;
    wbR[t] = bases[t] + counts[(size_t)blockIdx.x * NBA + t];
    wbC[t] = bases[NBA + t] + counts[(size_t)PB * NBA + (size_t)blockIdx.x * NBA + t];
    __syncthreads();
    int chunk = (nnz + PB - 1) / PB;
    int beg = blockIdx.x * chunk;
    int end = min(beg + chunk, nnz);
    for (int i = beg + threadIdx.x; i < end; i += 256) {
        int ro = rows[i], co = cols[i];
        unsigned vb = (unsigned)bfr(vals[i]) << 16;
        int rk = atomicAdd(&cR[ro >> 8], 1);
        stg_r[wbR[ro >> 8] + rk] = make_uint2(vb | (unsigned)co, (unsigned)ro);
        int ck = atomicAdd(&cC[co >> 8], 1);
        stg_c[wbC[co >> 8] + ck] = make_uint2(vb | (unsigned)ro, (unsigned)co);
    }
}

// k4: one block per (dir,bucket). Degrees come straight from deg (no counting
// pass over staging -- saves a full 25.6 MB read + 1.6M LDS atomics), scan,
// write rp coalesced, scatter final 4 B entries within the block's own ent
// window (single-CU -> single-L2 -> full-line writebacks).
__global__ __launch_bounds__(1024) void bucket_build(
    const uint2* __restrict__ stg_r, const uint2* __restrict__ stg_c,
    const int* __restrict__ deg_r, const int* __restrict__ deg_c,
    const int* __restrict__ totals, const int* __restrict__ bases,
    unsigned* __restrict__ ent_r, unsigned* __restrict__ ent_c,
    int* __restrict__ rp_r, int* __restrict__ rp_c, int n) {
    __shared__ int cnt[NBA];
    __shared__ int wsum[4], woff[4];
    int bkt = blockIdx.x, dir = blockIdx.y;
    const uint2* stg = dir ? stg_c : stg_r;
    const int* deg = dir ? deg_c : deg_r;
    unsigned* ent = dir ? ent_c : ent_r;
    int* rp = dir ? rp_c : rp_r;
    int base = bases[dir * NBA + bkt];
    int total = totals[dir * NBA + bkt];
    int lo = bkt << 8;
    int nb = min(NBA, n - lo);
    int tid = threadIdx.x;
    if (tid < NBA) cnt[tid] = (tid < nb) ? deg[lo + tid] : 0;
    __syncthreads();
    // exclusive scan of cnt[0..256) using waves 0..3
    int lane = tid & 63, wid = tid >> 6;
    int v = (tid < NBA) ? cnt[tid] : 0;
    int incl = v;
    #pragma unroll
    for (int off = 1; off < 64; off <<= 1) {
        int t = __shfl_up(incl, off);
        if (lane >= off) incl += t;
    }
    if (lane == 63 && wid < 4) wsum[wid] = incl;
    __syncthreads();
    if (tid == 0) {
        int run = 0;
        #pragma unroll
        for (int w = 0; w < 4; ++w) { woff[w] = run; run += wsum[w]; }
    }
    __syncthreads();
    if (tid < NBA) {
        int excl = woff[wid] + incl - v;
        if (tid < nb) rp[lo + tid] = base + excl;
        cnt[tid] = excl;               // own slot; becomes cursor
    }
    __syncthreads();
    for (int i = tid; i < total; i += 1024) {
        uint2 e = stg[base + i];
        int pos = atomicAdd(&cnt[(int)e.y - lo], 1);
        ent[base + pos] = e.x;
    }
}

// ---------- bf16-gather SpMM (+ optional fused leaky/LN/residual) ----------
// One wave per output row. Quarter-wave (16 lanes) x 16 B (8 bf16) covers a
// 256 B row; the 4 quarters process interleaved edges. The edge loop is
// fully predicated 4-wide: every quarter always has 4 independent gathers in
// flight regardless of degree (padded edges are clamped to end-1 and their
// value forced to 0 -> contribute exactly 0).
// Entry decode: val = bhi(e), src = e & 0xffff.
// post: 0 = none (bf16 out), 1 = leaky+LN+res (bf16 out), 2 = LN+res (fp32 out).
__global__ __launch_bounds__(256) void spmm_bf(
    const unsigned short* __restrict__ x, const int* __restrict__ rp,
    const unsigned* __restrict__ ent,
    const float* __restrict__ res, const float* __restrict__ gamma,
    const float* __restrict__ beta,
    unsigned short* __restrict__ out_bf, float* __restrict__ out_f32,
    int n, int post) {
    int wid = threadIdx.x >> 6, lane = threadIdx.x & 63;
    int row = blockIdx.x * 4 + wid;
    if (row >= n) return;
    int quarter = lane >> 4, q = lane & 15;
    int beg = rp[row], end = rp[row + 1];
    float acc[8];
    #pragma unroll
    for (int k = 0; k < 8; ++k) acc[k] = 0.f;

    int last = end - 1;
    for (int i0 = beg + quarter; i0 < end; i0 += 16) {
        int i1 = i0 + 4, i2 = i0 + 8, i3 = i0 + 12;
        unsigned e0 = ent[i0];
        unsigned e1 = ent[i1 < end ? i1 : last];
        unsigned e2 = ent[i2 < end ? i2 : last];
        unsigned e3 = ent[i3 < end ? i3 : last];
        uint4 u0 = ((const uint4*)(x + (size_t)(e0 & 0xffffu) * HD))[q];
        uint4 u1 = ((const uint4*)(x + (size_t)(e1 & 0xffffu) * HD))[q];
        uint4 u2 = ((const uint4*)(x + (size_t)(e2 & 0xffffu) * HD))[q];
        uint4 u3 = ((const uint4*)(x + (size_t)(e3 & 0xffffu) * HD))[q];
        float v0 = bhi(e0);
        float v1 = i1 < end ? bhi(e1) : 0.f;
        float v2 = i2 < end ? bhi(e2) : 0.f;
        float v3 = i3 < end ? bhi(e3) : 0.f;
        acc[0] += v0 * blo(u0.x) + v1 * blo(u1.x);
        acc[1] += v0 * bhi(u0.x) + v1 * bhi(u1.x);
        acc[2] += v0 * blo(u0.y) + v1 * blo(u1.y);
        acc[3] += v0 * bhi(u0.y) + v1 * bhi(u1.y);
        acc[4] += v0 * blo(u0.z) + v1 * blo(u1.z);
        acc[5] += v0 * bhi(u0.z) + v1 * bhi(u1.z);
        acc[6] += v0 * blo(u0.w) + v1 * blo(u1.w);
        acc[7] += v0 * bhi(u0.w) + v1 * bhi(u1.w);
        acc[0] += v2 * blo(u2.x) + v3 * blo(u3.x);
        acc[1] += v2 * bhi(u2.x) + v3 * bhi(u3.x);
        acc[2] += v2 * blo(u2.y) + v3 * blo(u3.y);
        acc[3] += v2 * bhi(u2.y) + v3 * bhi(u3.y);
        acc[4] += v2 * blo(u2.z) + v3 * blo(u3.z);
        acc[5] += v2 * bhi(u2.z) + v3 * bhi(u3.z);
        acc[6] += v2 * blo(u2.w) + v3 * blo(u3.w);
        acc[7] += v2 * bhi(u2.w) + v3 * bhi(u3.w);
    }
    // combine the 4 quarters
    #pragma unroll
    for (int k = 0; k < 8; ++k) {
        acc[k] += __shfl_xor(acc[k], 16);
        acc[k] += __shfl_xor(acc[k], 32);
    }
    if (quarter != 0) return;

    if (post == 0) {
        uint4 s;
        s.x = (unsigned)bfr(acc[0]) | ((unsigned)bfr(acc[1]) << 16);
        s.y = (unsigned)bfr(acc[2]) | ((unsigned)bfr(acc[3]) << 16);
        s.z = (unsigned)bfr(acc[4]) | ((unsigned)bfr(acc[5]) << 16);
        s.w = (unsigned)bfr(acc[6]) | ((unsigned)bfr(acc[7]) << 16);
        ((uint4*)(out_bf + (size_t)row * HD))[q] = s;
        return;
    }
    if (post == 1) {
        #pragma unroll
        for (int k = 0; k < 8; ++k) acc[k] = acc[k] >= 0.f ? acc[k] : LEAKY * acc[k];
    }
    float t = 0.f;
    #pragma unroll
    for (int k = 0; k < 8; ++k) t += acc[k];
    #pragma unroll
    for (int off = 1; off < 16; off <<= 1) t += __shfl_xor(t, off);
    float mu = t * (1.f / HD);
    float d[8], vs = 0.f;
    #pragma unroll
    for (int k = 0; k < 8; ++k) { d[k] = acc[k] - mu; vs += d[k] * d[k]; }
    #pragma unroll
    for (int off = 1; off < 16; off <<= 1) vs += __shfl_xor(vs, off);
    float inv = rsqrtf(vs * (1.f / HD) + LN_EPS);

    float4 g0 = ((const float4*)gamma)[2 * q], g1 = ((const float4*)gamma)[2 * q + 1];
    float4 b0 = ((const float4*)beta)[2 * q],  b1 = ((const float4*)beta)[2 * q + 1];
    float4 r0 = ((const float4*)(res + (size_t)row * HD))[2 * q];
    float4 r1 = ((const float4*)(res + (size_t)row * HD))[2 * q + 1];
    float o[8];
    o[0] = d[0] * inv * g0.x + b0.x + r0.x;
    o[1] = d[1] * inv * g0.y + b0.y + r0.y;
    o[2] = d[2] * inv * g0.z + b0.z + r0.z;
    o[3] = d[3] * inv * g0.w + b0.w + r0.w;
    o[4] = d[4] * inv * g1.x + b1.x + r1.x;
    o[5] = d[5] * inv * g1.y + b1.y + r1.y;
    o[6] = d[6] * inv * g1.z + b1.z + r1.z;
    o[7] = d[7] * inv * g1.w + b1.w + r1.w;
    if (post == 1) {
        uint4 s;
        s.x = (unsigned)bfr(o[0]) | ((unsigned)bfr(o[1]) << 16);
        s.y = (unsigned)bfr(o[2]) | ((unsigned)bfr(o[3]) << 16);
        s.z = (unsigned)bfr(o[4]) | ((unsigned)bfr(o[5]) << 16);
        s.w = (unsigned)bfr(o[6]) | ((unsigned)bfr(o[7]) << 16);
        ((uint4*)(out_bf + (size_t)row * HD))[q] = s;
    } else {
        float4 s0 = {o[0], o[1], o[2], o[3]};
        float4 s1 = {o[4], o[5], o[6], o[7]};
        ((float4*)(out_f32 + (size_t)row * HD))[2 * q] = s0;
        ((float4*)(out_f32 + (size_t)row * HD))[2 * q + 1] = s1;
    }
}

extern "C" void kernel_launch(void* const* d_in, const int* in_sizes, int n_in,
                              void* d_out, int out_size, void* d_ws, size_t ws_size,
                              hipStream_t stream) {
    const float* ego   = (const float*)d_in[0];
    const float* vals  = (const float*)d_in[1];
    const float* gamma = (const float*)d_in[2];
    const float* beta  = (const float*)d_in[3];
    const int*   rows  = (const int*)d_in[4];
    const int*   cols  = (const int*)d_in[5];

    const int N   = in_sizes[0] / HD;   // 50000 (< 65536 for 16-bit node ids)
    const int NNZ = in_sizes[1];        // 800000
    const int NBK = (N + 255) >> 8;     // 196 buckets (<= 256)

    float* out = (float*)d_out;
    char* w = (char*)d_ws;
    unsigned short* ego_bf = (unsigned short*)w; w += (size_t)N * HD * 2;
    unsigned short* bufA   = (unsigned short*)w; w += (size_t)N * HD * 2;
    unsigned short* bufB   = (unsigned short*)w; w += (size_t)N * HD * 2;  // aliases stg
    int*  rp_r = (int*)w;  w += (size_t)(N + 4) * 4;
    int*  rp_c = (int*)w;  w += (size_t)(N + 4) * 4;
    unsigned* ent_r = (unsigned*)w; w += (size_t)NNZ * 4;
    unsigned* ent_c = (unsigned*)w; w += (size_t)NNZ * 4;
    int* counts = (int*)w; w += (size_t)2 * PB * NBA * 4;
    int* deg_r  = (int*)w; w += (size_t)N * 4;   // deg_r, deg_c contiguous
    int* deg_c  = (int*)w; w += (size_t)N * 4;
    int* totals = (int*)w; w += (size_t)2 * NBA * 4;
    int* bases  = (int*)w; w += (size_t)2 * NBA * 4;

    // staging aliases bufB (2*NNZ*8 = 12.8 MB = bufB size; consumed by
    // bucket_build, which runs before spmm #2 writes bufB).
    uint2* stg_r = (uint2*)bufB;
    uint2* stg_c = stg_r + NNZ;

    // ---- build both CSRs + bf16 ego ----
    conv_zero<<<2048, 256, 0, stream>>>(ego, ego_bf, N * HD / 4, deg_r, 2 * N);
    part_count<<<PB, 256, 0, stream>>>(rows, cols, counts, deg_r, deg_c, NNZ);
    part_off<<<dim3(NBK, 2), 64, 0, stream>>>(counts, totals);
    base_scan<<<1, 128, 0, stream>>>(totals, bases, rp_r, rp_c, NBK, N, NNZ);
    part_scatter<<<PB, 256, 0, stream>>>(rows, cols, vals, counts, bases,
                                         stg_r, stg_c, NNZ);
    bucket_build<<<dim3(NBK, 2), 1024, 0, stream>>>(stg_r, stg_c, deg_r, deg_c,
                                                    totals, bases,
                                                    ent_r, ent_c, rp_r, rp_c, N);

    const int sblocks = (N + 3) / 4;

    // ---- layer 0 ----
    spmm_bf<<<sblocks, 256, 0, stream>>>(ego_bf, rp_c, ent_c,
                                         nullptr, nullptr, nullptr, bufA, nullptr, N, 0);
    spmm_bf<<<sblocks, 256, 0, stream>>>(bufA, rp_r, ent_r,
                                         ego, gamma, beta, bufB, nullptr, N, 1);
    // ---- layer 1 ----
    spmm_bf<<<sblocks, 256, 0, stream>>>(bufB, rp_c, ent_c,
                                         nullptr, nullptr, nullptr, bufA, nullptr, N, 0);
    spmm_bf<<<sblocks, 256, 0, stream>>>(bufA, rp_r, ent_r,
                                         ego, gamma + HD, beta + HD, nullptr, out, N, 2);
}

// Round 10
// 246.665 us; speedup vs baseline: 1.6229x; 1.2402x over previous
//
#include <hip/hip_runtime.h>
#include <hip/hip_bf16.h>

#define HD 128
#define PB 256         // partition blocks
#define NBA 256        // max buckets (node >> 8); array stride
#define LEAKY 0.2f
#define LN_EPS 1e-5f

// ---- bf16 helpers (manual, RNE) ----
__device__ __forceinline__ unsigned short bfr(float f) {
    unsigned int b = __float_as_uint(f);
    return (unsigned short)((b + 0x7fffu + ((b >> 16) & 1u)) >> 16);
}
__device__ __forceinline__ float blo(unsigned int u) { return __uint_as_float(u << 16); }
__device__ __forceinline__ float bhi(unsigned int u) { return __uint_as_float(u & 0xffff0000u); }

// ---------- fp32 -> bf16 conversion (ego) ----------
__global__ __launch_bounds__(256) void f32_to_bf16(
    const float* __restrict__ x, unsigned short* __restrict__ y, int n4) {
    int i = blockIdx.x * 256 + threadIdx.x;
    if (i >= n4) return;
    float4 f = ((const float4*)x)[i];
    ushort4 u;
    u.x = bfr(f.x); u.y = bfr(f.y); u.z = bfr(f.z); u.w = bfr(f.w);
    ((ushort4*)y)[i] = u;
}

// ---------- CSR build: two-level bucket partition (zero global atomics) ----
// Bucket of node b = b >> 8 (256 nodes/bucket, NBK=196 for N=50000).
// counts layout: counts[dir*PB*NBA + blk*NBA + bkt].
// Round-6/8 lesson: NO per-node global atomics anywhere -- scattered atomics
// across 8 non-coherent XCD L2s cause ~32B/atomic line-writeback traffic
// (measured 50-105 MB WRITE_SIZE, +50..+150us). All histograms live in LDS;
// all global writes are block-exclusive contiguous ranges.

// k1: per-block bucket counts for both directions.
__global__ __launch_bounds__(256) void part_count(
    const int* __restrict__ rows, const int* __restrict__ cols,
    int* __restrict__ counts, int nnz) {
    __shared__ int cR[NBA], cC[NBA];
    cR[threadIdx.x] = 0; cC[threadIdx.x] = 0;
    __syncthreads();
    int chunk = (nnz + PB - 1) / PB;
    int beg = blockIdx.x * chunk;
    int end = min(beg + chunk, nnz);
    for (int i = beg + threadIdx.x; i < end; i += 256) {
        atomicAdd(&cR[rows[i] >> 8], 1);
        atomicAdd(&cC[cols[i] >> 8], 1);
    }
    __syncthreads();
    counts[(size_t)blockIdx.x * NBA + threadIdx.x] = cR[threadIdx.x];
    counts[(size_t)PB * NBA + (size_t)blockIdx.x * NBA + threadIdx.x] = cC[threadIdx.x];
}

// k2a: for each (dir,bucket), exclusive scan over PB block counts (in-place
// counts -> offsets), emit totals[dir*NBA+bkt]. One wave per block.
__global__ __launch_bounds__(64) void part_off(
    int* __restrict__ counts, int* __restrict__ totals) {
    int bkt = blockIdx.x, dir = blockIdx.y, lane = threadIdx.x;
    int* p = counts + (size_t)dir * PB * NBA;
    int v[4], s = 0;
    #pragma unroll
    for (int j = 0; j < 4; ++j) {
        int blk = lane * 4 + j;
        v[j] = p[(size_t)blk * NBA + bkt];
        s += v[j];
    }
    int incl = s;
    #pragma unroll
    for (int off = 1; off < 64; off <<= 1) {
        int t = __shfl_up(incl, off);
        if (lane >= off) incl += t;
    }
    int excl = incl - s;
    #pragma unroll
    for (int j = 0; j < 4; ++j) {
        int blk = lane * 4 + j;
        p[(size_t)blk * NBA + bkt] = excl;
        excl += v[j];
    }
    if (lane == 63) totals[dir * NBA + bkt] = incl;
}

// k2b: bucket bases (exclusive scan of up to 256 totals per dir; one wave per
// dir, 4 buckets per lane), plus rp[N] = nnz.
__global__ __launch_bounds__(128) void base_scan(
    const int* __restrict__ totals, int* __restrict__ bases,
    int* __restrict__ rp_r, int* __restrict__ rp_c, int nbk, int n, int nnz) {
    int dir = threadIdx.x >> 6, lane = threadIdx.x & 63;
    int v[4], s = 0;
    #pragma unroll
    for (int j = 0; j < 4; ++j) {
        int b = lane * 4 + j;
        v[j] = (b < nbk) ? totals[dir * NBA + b] : 0;
        s += v[j];
    }
    int incl = s;
    #pragma unroll
    for (int off = 1; off < 64; off <<= 1) {
        int t = __shfl_up(incl, off);
        if (lane >= off) incl += t;
    }
    int excl = incl - s;
    #pragma unroll
    for (int j = 0; j < 4; ++j) {
        bases[dir * NBA + lane * 4 + j] = excl;
        excl += v[j];
    }
    if (lane == 0) (dir ? rp_c : rp_r)[n] = nnz;
}

// k3: scatter edges into bucket-major staging: stg[dir] entry = (payload, bin),
// payload = other | (bf16(val) << 16). Per-(block,bucket) destination ranges
// are contiguous -> block-exclusive line assembly.
__global__ __launch_bounds__(256) void part_scatter(
    const int* __restrict__ rows, const int* __restrict__ cols,
    const float* __restrict__ vals,
    const int* __restrict__ counts, const int* __restrict__ bases,
    uint2* __restrict__ stg_r, uint2* __restrict__ stg_c, int nnz) {
    __shared__ int cR[NBA], cC[NBA], wbR[NBA], wbC[NBA];
    int t = threadIdx.x;
    cR[t] = 0; cC[t] = 0;
    wbR[t] = bases[t] + counts[(size_t)blockIdx.x * NBA + t];
    wbC[t] = bases[NBA + t] + counts[(size_t)PB * NBA + (size_t)blockIdx.x * NBA + t];
    __syncthreads();
    int chunk = (nnz + PB - 1) / PB;
    int beg = blockIdx.x * chunk;
    int end = min(beg + chunk, nnz);
    for (int i = beg + threadIdx.x; i < end; i += 256) {
        int ro = rows[i], co = cols[i];
        unsigned vb = (unsigned)bfr(vals[i]) << 16;
        int rk = atomicAdd(&cR[ro >> 8], 1);
        stg_r[wbR[ro >> 8] + rk] = make_uint2(vb | (unsigned)co, (unsigned)ro);
        int ck = atomicAdd(&cC[co >> 8], 1);
        stg_c[wbC[co >> 8] + ck] = make_uint2(vb | (unsigned)ro, (unsigned)co);
    }
}

// k4: one block per (dir,bucket). Count bins in LDS, scan, write rp
// coalesced, scatter final 4 B entries within the block's own ent window
// (single-CU -> single-L2 -> full-line writebacks). 256-node buckets give
// 2*NBK = 392 workgroups (full CU coverage).
__global__ __launch_bounds__(1024) void bucket_build(
    const uint2* __restrict__ stg_r, const uint2* __restrict__ stg_c,
    const int* __restrict__ totals, const int* __restrict__ bases,
    unsigned* __restrict__ ent_r, unsigned* __restrict__ ent_c,
    int* __restrict__ rp_r, int* __restrict__ rp_c, int n) {
    __shared__ int cnt[NBA];
    __shared__ int wsum[4], woff[4];
    int bkt = blockIdx.x, dir = blockIdx.y;
    const uint2* stg = dir ? stg_c : stg_r;
    unsigned* ent = dir ? ent_c : ent_r;
    int* rp = dir ? rp_c : rp_r;
    int base = bases[dir * NBA + bkt];
    int total = totals[dir * NBA + bkt];
    int lo = bkt << 8;
    int nb = min(NBA, n - lo);
    int tid = threadIdx.x;
    if (tid < NBA) cnt[tid] = 0;
    __syncthreads();
    for (int i = tid; i < total; i += 1024)
        atomicAdd(&cnt[(int)stg[base + i].y - lo], 1);
    __syncthreads();
    // exclusive scan of cnt[0..256) using waves 0..3
    int lane = tid & 63, wid = tid >> 6;
    int v = (tid < NBA) ? cnt[tid] : 0;
    int incl = v;
    #pragma unroll
    for (int off = 1; off < 64; off <<= 1) {
        int t = __shfl_up(incl, off);
        if (lane >= off) incl += t;
    }
    if (lane == 63 && wid < 4) wsum[wid] = incl;
    __syncthreads();
    if (tid == 0) {
        int run = 0;
        #pragma unroll
        for (int w = 0; w < 4; ++w) { woff[w] = run; run += wsum[w]; }
    }
    __syncthreads();
    if (tid < NBA) {
        int excl = woff[wid] + incl - v;
        if (tid < nb) rp[lo + tid] = base + excl;
        cnt[tid] = excl;               // own slot; becomes cursor
    }
    __syncthreads();
    for (int i = tid; i < total; i += 1024) {
        uint2 e = stg[base + i];
        int pos = atomicAdd(&cnt[(int)e.y - lo], 1);
        ent[base + pos] = e.x;
    }
}

// ---------- bf16-gather SpMM (+ optional fused leaky/LN/residual) ----------
// One wave per output row. Quarter-wave (16 lanes) x 16 B (8 bf16) covers a
// 256 B row; the 4 quarters process interleaved edges. The edge loop is
// fully predicated 4-wide: every quarter always has 4 independent gathers in
// flight regardless of degree (padded edges are clamped to end-1 and their
// value forced to 0 -> contribute exactly 0).
// Entry decode: val = bhi(e), src = e & 0xffff.
// post: 0 = none (bf16 out), 1 = leaky+LN+res (bf16 out), 2 = LN+res (fp32 out).
__global__ __launch_bounds__(256) void spmm_bf(
    const unsigned short* __restrict__ x, const int* __restrict__ rp,
    const unsigned* __restrict__ ent,
    const float* __restrict__ res, const float* __restrict__ gamma,
    const float* __restrict__ beta,
    unsigned short* __restrict__ out_bf, float* __restrict__ out_f32,
    int n, int post) {
    int wid = threadIdx.x >> 6, lane = threadIdx.x & 63;
    int row = blockIdx.x * 4 + wid;
    if (row >= n) return;
    int quarter = lane >> 4, q = lane & 15;
    int beg = rp[row], end = rp[row + 1];
    float acc[8];
    #pragma unroll
    for (int k = 0; k < 8; ++k) acc[k] = 0.f;

    int last = end - 1;
    for (int i0 = beg + quarter; i0 < end; i0 += 16) {
        int i1 = i0 + 4, i2 = i0 + 8, i3 = i0 + 12;
        unsigned e0 = ent[i0];
        unsigned e1 = ent[i1 < end ? i1 : last];
        unsigned e2 = ent[i2 < end ? i2 : last];
        unsigned e3 = ent[i3 < end ? i3 : last];
        uint4 u0 = ((const uint4*)(x + (size_t)(e0 & 0xffffu) * HD))[q];
        uint4 u1 = ((const uint4*)(x + (size_t)(e1 & 0xffffu) * HD))[q];
        uint4 u2 = ((const uint4*)(x + (size_t)(e2 & 0xffffu) * HD))[q];
        uint4 u3 = ((const uint4*)(x + (size_t)(e3 & 0xffffu) * HD))[q];
        float v0 = bhi(e0);
        float v1 = i1 < end ? bhi(e1) : 0.f;
        float v2 = i2 < end ? bhi(e2) : 0.f;
        float v3 = i3 < end ? bhi(e3) : 0.f;
        acc[0] += v0 * blo(u0.x) + v1 * blo(u1.x);
        acc[1] += v0 * bhi(u0.x) + v1 * bhi(u1.x);
        acc[2] += v0 * blo(u0.y) + v1 * blo(u1.y);
        acc[3] += v0 * bhi(u0.y) + v1 * bhi(u1.y);
        acc[4] += v0 * blo(u0.z) + v1 * blo(u1.z);
        acc[5] += v0 * bhi(u0.z) + v1 * bhi(u1.z);
        acc[6] += v0 * blo(u0.w) + v1 * blo(u1.w);
        acc[7] += v0 * bhi(u0.w) + v1 * bhi(u1.w);
        acc[0] += v2 * blo(u2.x) + v3 * blo(u3.x);
        acc[1] += v2 * bhi(u2.x) + v3 * bhi(u3.x);
        acc[2] += v2 * blo(u2.y) + v3 * blo(u3.y);
        acc[3] += v2 * bhi(u2.y) + v3 * bhi(u3.y);
        acc[4] += v2 * blo(u2.z) + v3 * blo(u3.z);
        acc[5] += v2 * bhi(u2.z) + v3 * bhi(u3.z);
        acc[6] += v2 * blo(u2.w) + v3 * blo(u3.w);
        acc[7] += v2 * bhi(u2.w) + v3 * bhi(u3.w);
    }
    // combine the 4 quarters
    #pragma unroll
    for (int k = 0; k < 8; ++k) {
        acc[k] += __shfl_xor(acc[k], 16);
        acc[k] += __shfl_xor(acc[k], 32);
    }
    if (quarter != 0) return;

    if (post == 0) {
        uint4 s;
        s.x = (unsigned)bfr(acc[0]) | ((unsigned)bfr(acc[1]) << 16);
        s.y = (unsigned)bfr(acc[2]) | ((unsigned)bfr(acc[3]) << 16);
        s.z = (unsigned)bfr(acc[4]) | ((unsigned)bfr(acc[5]) << 16);
        s.w = (unsigned)bfr(acc[6]) | ((unsigned)bfr(acc[7]) << 16);
        ((uint4*)(out_bf + (size_t)row * HD))[q] = s;
        return;
    }
    if (post == 1) {
        #pragma unroll
        for (int k = 0; k < 8; ++k) acc[k] = acc[k] >= 0.f ? acc[k] : LEAKY * acc[k];
    }
    float t = 0.f;
    #pragma unroll
    for (int k = 0; k < 8; ++k) t += acc[k];
    #pragma unroll
    for (int off = 1; off < 16; off <<= 1) t += __shfl_xor(t, off);
    float mu = t * (1.f / HD);
    float d[8], vs = 0.f;
    #pragma unroll
    for (int k = 0; k < 8; ++k) { d[k] = acc[k] - mu; vs += d[k] * d[k]; }
    #pragma unroll
    for (int off = 1; off < 16; off <<= 1) vs += __shfl_xor(vs, off);
    float inv = rsqrtf(vs * (1.f / HD) + LN_EPS);

    float4 g0 = ((const float4*)gamma)[2 * q], g1 = ((const float4*)gamma)[2 * q + 1];
    float4 b0 = ((const float4*)beta)[2 * q],  b1 = ((const float4*)beta)[2 * q + 1];
    float4 r0 = ((const float4*)(res + (size_t)row * HD))[2 * q];
    float4 r1 = ((const float4*)(res + (size_t)row * HD))[2 * q + 1];
    float o[8];
    o[0] = d[0] * inv * g0.x + b0.x + r0.x;
    o[1] = d[1] * inv * g0.y + b0.y + r0.y;
    o[2] = d[2] * inv * g0.z + b0.z + r0.z;
    o[3] = d[3] * inv * g0.w + b0.w + r0.w;
    o[4] = d[4] * inv * g1.x + b1.x + r1.x;
    o[5] = d[5] * inv * g1.y + b1.y + r1.y;
    o[6] = d[6] * inv * g1.z + b1.z + r1.z;
    o[7] = d[7] * inv * g1.w + b1.w + r1.w;
    if (post == 1) {
        uint4 s;
        s.x = (unsigned)bfr(o[0]) | ((unsigned)bfr(o[1]) << 16);
        s.y = (unsigned)bfr(o[2]) | ((unsigned)bfr(o[3]) << 16);
        s.z = (unsigned)bfr(o[4]) | ((unsigned)bfr(o[5]) << 16);
        s.w = (unsigned)bfr(o[6]) | ((unsigned)bfr(o[7]) << 16);
        ((uint4*)(out_bf + (size_t)row * HD))[q] = s;
    } else {
        float4 s0 = {o[0], o[1], o[2], o[3]};
        float4 s1 = {o[4], o[5], o[6], o[7]};
        ((float4*)(out_f32 + (size_t)row * HD))[2 * q] = s0;
        ((float4*)(out_f32 + (size_t)row * HD))[2 * q + 1] = s1;
    }
}

extern "C" void kernel_launch(void* const* d_in, const int* in_sizes, int n_in,
                              void* d_out, int out_size, void* d_ws, size_t ws_size,
                              hipStream_t stream) {
    const float* ego   = (const float*)d_in[0];
    const float* vals  = (const float*)d_in[1];
    const float* gamma = (const float*)d_in[2];
    const float* beta  = (const float*)d_in[3];
    const int*   rows  = (const int*)d_in[4];
    const int*   cols  = (const int*)d_in[5];

    const int N   = in_sizes[0] / HD;   // 50000 (< 65536 for 16-bit node ids)
    const int NNZ = in_sizes[1];        // 800000
    const int NBK = (N + 255) >> 8;     // 196 buckets (<= 256)

    float* out = (float*)d_out;
    char* w = (char*)d_ws;
    unsigned short* ego_bf = (unsigned short*)w; w += (size_t)N * HD * 2;
    unsigned short* bufA   = (unsigned short*)w; w += (size_t)N * HD * 2;
    unsigned short* bufB   = (unsigned short*)w; w += (size_t)N * HD * 2;  // aliases stg
    int*  rp_r = (int*)w;  w += (size_t)(N + 4) * 4;
    int*  rp_c = (int*)w;  w += (size_t)(N + 4) * 4;
    unsigned* ent_r = (unsigned*)w; w += (size_t)NNZ * 4;
    unsigned* ent_c = (unsigned*)w; w += (size_t)NNZ * 4;
    int* counts = (int*)w; w += (size_t)2 * PB * NBA * 4;
    int* totals = (int*)w; w += (size_t)2 * NBA * 4;
    int* bases  = (int*)w; w += (size_t)2 * NBA * 4;

    // staging aliases bufB (2*NNZ*8 = 12.8 MB = bufB size; consumed by
    // bucket_build, which runs before spmm #2 writes bufB).
    uint2* stg_r = (uint2*)bufB;
    uint2* stg_c = stg_r + NNZ;

    // ---- build both CSRs + bf16 ego ----
    f32_to_bf16<<<(N * HD / 4 + 255) / 256, 256, 0, stream>>>(ego, ego_bf, N * HD / 4);
    part_count<<<PB, 256, 0, stream>>>(rows, cols, counts, NNZ);
    part_off<<<dim3(NBK, 2), 64, 0, stream>>>(counts, totals);
    base_scan<<<1, 128, 0, stream>>>(totals, bases, rp_r, rp_c, NBK, N, NNZ);
    part_scatter<<<PB, 256, 0, stream>>>(rows, cols, vals, counts, bases,
                                         stg_r, stg_c, NNZ);
    bucket_build<<<dim3(NBK, 2), 1024, 0, stream>>>(stg_r, stg_c, totals, bases,
                                                    ent_r, ent_c, rp_r, rp_c, N);

    const int sblocks = (N + 3) / 4;

    // ---- layer 0 ----
    spmm_bf<<<sblocks, 256, 0, stream>>>(ego_bf, rp_c, ent_c,
                                         nullptr, nullptr, nullptr, bufA, nullptr, N, 0);
    spmm_bf<<<sblocks, 256, 0, stream>>>(bufA, rp_r, ent_r,
                                         ego, gamma, beta, bufB, nullptr, N, 1);
    // ---- layer 1 ----
    spmm_bf<<<sblocks, 256, 0, stream>>>(bufB, rp_c, ent_c,
                                         nullptr, nullptr, nullptr, bufA, nullptr, N, 0);
    spmm_bf<<<sblocks, 256, 0, stream>>>(bufA, rp_r, ent_r,
                                         ego, gamma + HD, beta + HD, nullptr, out, N, 2);
}

// Round 18
// 246.493 us; speedup vs baseline: 1.6240x; 1.0007x over previous
//
#include <hip/hip_runtime.h>
#include <hip/hip_bf16.h>

#define HD 128
#define PB 256         // partition blocks
#define NBA 256        // max buckets (node >> 8); array stride
#define BB_CAP 6144    // LDS edge-cache capacity in bucket_build (mean 4082, +32 sigma)
#define LEAKY 0.2f
#define LN_EPS 1e-5f

// ---- bf16 helpers (manual, RNE) ----
__device__ __forceinline__ unsigned short bfr(float f) {
    unsigned int b = __float_as_uint(f);
    return (unsigned short)((b + 0x7fffu + ((b >> 16) & 1u)) >> 16);
}
__device__ __forceinline__ float blo(unsigned int u) { return __uint_as_float(u << 16); }
__device__ __forceinline__ float bhi(unsigned int u) { return __uint_as_float(u & 0xffff0000u); }

// ---------- fp32 -> bf16 conversion (ego) ----------
__global__ __launch_bounds__(256) void f32_to_bf16(
    const float* __restrict__ x, unsigned short* __restrict__ y, int n4) {
    int i = blockIdx.x * 256 + threadIdx.x;
    if (i >= n4) return;
    float4 f = ((const float4*)x)[i];
    ushort4 u;
    u.x = bfr(f.x); u.y = bfr(f.y); u.z = bfr(f.z); u.w = bfr(f.w);
    ((ushort4*)y)[i] = u;
}

// ---------- CSR build: two-level bucket partition (zero global atomics) ----
// Bucket of node b = b >> 8 (256 nodes/bucket, NBK=196 for N=50000).
// counts layout: counts[dir*PB*NBA + blk*NBA + bkt].
// Round-6/8 lesson: NO per-node global atomics anywhere -- scattered atomics
// across 8 non-coherent XCD L2s cause ~32B/atomic line-writeback traffic
// (measured 50-105 MB WRITE_SIZE, +50..+150us). All histograms live in LDS;
// all global writes are block-exclusive contiguous ranges.

// k1: per-block bucket counts for both directions.
__global__ __launch_bounds__(256) void part_count(
    const int* __restrict__ rows, const int* __restrict__ cols,
    int* __restrict__ counts, int nnz) {
    __shared__ int cR[NBA], cC[NBA];
    cR[threadIdx.x] = 0; cC[threadIdx.x] = 0;
    __syncthreads();
    int chunk = (nnz + PB - 1) / PB;
    int beg = blockIdx.x * chunk;
    int end = min(beg + chunk, nnz);
    for (int i = beg + threadIdx.x; i < end; i += 256) {
        atomicAdd(&cR[rows[i] >> 8], 1);
        atomicAdd(&cC[cols[i] >> 8], 1);
    }
    __syncthreads();
    counts[(size_t)blockIdx.x * NBA + threadIdx.x] = cR[threadIdx.x];
    counts[(size_t)PB * NBA + (size_t)blockIdx.x * NBA + threadIdx.x] = cC[threadIdx.x];
}

// k2a: for each (dir,bucket), exclusive scan over PB block counts (in-place
// counts -> offsets), emit totals[dir*NBA+bkt]. One wave per block.
__global__ __launch_bounds__(64) void part_off(
    int* __restrict__ counts, int* __restrict__ totals) {
    int bkt = blockIdx.x, dir = blockIdx.y, lane = threadIdx.x;
    int* p = counts + (size_t)dir * PB * NBA;
    int v[4], s = 0;
    #pragma unroll
    for (int j = 0; j < 4; ++j) {
        int blk = lane * 4 + j;
        v[j] = p[(size_t)blk * NBA + bkt];
        s += v[j];
    }
    int incl = s;
    #pragma unroll
    for (int off = 1; off < 64; off <<= 1) {
        int t = __shfl_up(incl, off);
        if (lane >= off) incl += t;
    }
    int excl = incl - s;
    #pragma unroll
    for (int j = 0; j < 4; ++j) {
        int blk = lane * 4 + j;
        p[(size_t)blk * NBA + bkt] = excl;
        excl += v[j];
    }
    if (lane == 63) totals[dir * NBA + bkt] = incl;
}

// k2b: bucket bases (exclusive scan of up to 256 totals per dir; one wave per
// dir, 4 buckets per lane), plus rp[N] = nnz.
__global__ __launch_bounds__(128) void base_scan(
    const int* __restrict__ totals, int* __restrict__ bases,
    int* __restrict__ rp_r, int* __restrict__ rp_c, int nbk, int n, int nnz) {
    int dir = threadIdx.x >> 6, lane = threadIdx.x & 63;
    int v[4], s = 0;
    #pragma unroll
    for (int j = 0; j < 4; ++j) {
        int b = lane * 4 + j;
        v[j] = (b < nbk) ? totals[dir * NBA + b] : 0;
        s += v[j];
    }
    int incl = s;
    #pragma unroll
    for (int off = 1; off < 64; off <<= 1) {
        int t = __shfl_up(incl, off);
        if (lane >= off) incl += t;
    }
    int excl = incl - s;
    #pragma unroll
    for (int j = 0; j < 4; ++j) {
        bases[dir * NBA + lane * 4 + j] = excl;
        excl += v[j];
    }
    if (lane == 0) (dir ? rp_c : rp_r)[n] = nnz;
}

// k3: scatter edges into bucket-major staging: stg[dir] entry = (payload, bin),
// payload = other | (bf16(val) << 16). Per-(block,bucket) destination ranges
// are contiguous -> block-exclusive line assembly.
__global__ __launch_bounds__(256) void part_scatter(
    const int* __restrict__ rows, const int* __restrict__ cols,
    const float* __restrict__ vals,
    const int* __restrict__ counts, const int* __restrict__ bases,
    uint2* __restrict__ stg_r, uint2* __restrict__ stg_c, int nnz) {
    __shared__ int cR[NBA], cC[NBA], wbR[NBA], wbC[NBA];
    int t = threadIdx.x;
    cR[t] = 0; cC[t] = 0;
    wbR[t] = bases[t] + counts[(size_t)blockIdx.x * NBA + t];
    wbC[t] = bases[NBA + t] + counts[(size_t)PB * NBA + (size_t)blockIdx.x * NBA + t];
    __syncthreads();
    int chunk = (nnz + PB - 1) / PB;
    int beg = blockIdx.x * chunk;
    int end = min(beg + chunk, nnz);
    for (int i = beg + threadIdx.x; i < end; i += 256) {
        int ro = rows[i], co = cols[i];
        unsigned vb = (unsigned)bfr(vals[i]) << 16;
        int rk = atomicAdd(&cR[ro >> 8], 1);
        stg_r[wbR[ro >> 8] + rk] = make_uint2(vb | (unsigned)co, (unsigned)ro);
        int ck = atomicAdd(&cC[co >> 8], 1);
        stg_c[wbC[co >> 8] + ck] = make_uint2(vb | (unsigned)ro, (unsigned)co);
    }
}

// k4: one block per (dir,bucket). NEW: staging is read from global exactly
// ONCE into an LDS edge cache (payload u32 + bin u16, 37 KB; bucket totals
// are ~4082 +/- 64, BB_CAP=6144 is +32 sigma). Count bins during the load,
// scan, write rp coalesced, then scatter from LDS into the block's own ent
// window (single-CU -> single-L2 -> full-line writebacks). Fallback to the
// measured-good 2-pass global path if a bucket ever exceeds BB_CAP.
__global__ __launch_bounds__(1024) void bucket_build(
    const uint2* __restrict__ stg_r, const uint2* __restrict__ stg_c,
    const int* __restrict__ totals, const int* __restrict__ bases,
    unsigned* __restrict__ ent_r, unsigned* __restrict__ ent_c,
    int* __restrict__ rp_r, int* __restrict__ rp_c, int n) {
    __shared__ unsigned spay[BB_CAP];
    __shared__ unsigned short sbin[BB_CAP];
    __shared__ int cnt[NBA];
    __shared__ int wsum[4], woff[4];
    int bkt = blockIdx.x, dir = blockIdx.y;
    const uint2* stg = dir ? stg_c : stg_r;
    unsigned* ent = dir ? ent_c : ent_r;
    int* rp = dir ? rp_c : rp_r;
    int base = bases[dir * NBA + bkt];
    int total = totals[dir * NBA + bkt];
    int lo = bkt << 8;
    int nb = min(NBA, n - lo);
    int tid = threadIdx.x;
    if (tid < NBA) cnt[tid] = 0;
    __syncthreads();
    bool fits = (total <= BB_CAP);
    if (fits) {
        for (int i = tid; i < total; i += 1024) {
            uint2 e = stg[base + i];
            int b = (int)e.y - lo;
            spay[i] = e.x;
            sbin[i] = (unsigned short)b;
            atomicAdd(&cnt[b], 1);
        }
    } else {
        for (int i = tid; i < total; i += 1024)
            atomicAdd(&cnt[(int)stg[base + i].y - lo], 1);
    }
    __syncthreads();
    // exclusive scan of cnt[0..256) using waves 0..3
    int lane = tid & 63, wid = tid >> 6;
    int v = (tid < NBA) ? cnt[tid] : 0;
    int incl = v;
    #pragma unroll
    for (int off = 1; off < 64; off <<= 1) {
        int t = __shfl_up(incl, off);
        if (lane >= off) incl += t;
    }
    if (lane == 63 && wid < 4) wsum[wid] = incl;
    __syncthreads();
    if (tid == 0) {
        int run = 0;
        #pragma unroll
        for (int w = 0; w < 4; ++w) { woff[w] = run; run += wsum[w]; }
    }
    __syncthreads();
    if (tid < NBA) {
        int excl = woff[wid] + incl - v;
        if (tid < nb) rp[lo + tid] = base + excl;
        cnt[tid] = excl;               // own slot; becomes cursor
    }
    __syncthreads();
    if (fits) {
        for (int i = tid; i < total; i += 1024) {
            int b = sbin[i];
            int pos = atomicAdd(&cnt[b], 1);
            ent[base + pos] = spay[i];
        }
    } else {
        for (int i = tid; i < total; i += 1024) {
            uint2 e = stg[base + i];
            int pos = atomicAdd(&cnt[(int)e.y - lo], 1);
            ent[base + pos] = e.x;
        }
    }
}

// ---------- bf16-gather SpMM (+ optional fused leaky/LN/residual) ----------
// One wave per output row. Quarter-wave (16 lanes) x 16 B (8 bf16) covers a
// 256 B row; the 4 quarters process interleaved edges. The edge loop is
// fully predicated 4-wide: every quarter always has 4 independent gathers in
// flight regardless of degree (padded edges are clamped to end-1 and their
// value forced to 0 -> contribute exactly 0).
// Entry decode: val = bhi(e), src = e & 0xffff.
// post: 0 = none (bf16 out), 1 = leaky+LN+res (bf16 out), 2 = LN+res (fp32 out).
__global__ __launch_bounds__(256) void spmm_bf(
    const unsigned short* __restrict__ x, const int* __restrict__ rp,
    const unsigned* __restrict__ ent,
    const float* __restrict__ res, const float* __restrict__ gamma,
    const float* __restrict__ beta,
    unsigned short* __restrict__ out_bf, float* __restrict__ out_f32,
    int n, int post) {
    int wid = threadIdx.x >> 6, lane = threadIdx.x & 63;
    int row = blockIdx.x * 4 + wid;
    if (row >= n) return;
    int quarter = lane >> 4, q = lane & 15;
    int beg = rp[row], end = rp[row + 1];
    float acc[8];
    #pragma unroll
    for (int k = 0; k < 8; ++k) acc[k] = 0.f;

    int last = end - 1;
    for (int i0 = beg + quarter; i0 < end; i0 += 16) {
        int i1 = i0 + 4, i2 = i0 + 8, i3 = i0 + 12;
        unsigned e0 = ent[i0];
        unsigned e1 = ent[i1 < end ? i1 : last];
        unsigned e2 = ent[i2 < end ? i2 : last];
        unsigned e3 = ent[i3 < end ? i3 : last];
        uint4 u0 = ((const uint4*)(x + (size_t)(e0 & 0xffffu) * HD))[q];
        uint4 u1 = ((const uint4*)(x + (size_t)(e1 & 0xffffu) * HD))[q];
        uint4 u2 = ((const uint4*)(x + (size_t)(e2 & 0xffffu) * HD))[q];
        uint4 u3 = ((const uint4*)(x + (size_t)(e3 & 0xffffu) * HD))[q];
        float v0 = bhi(e0);
        float v1 = i1 < end ? bhi(e1) : 0.f;
        float v2 = i2 < end ? bhi(e2) : 0.f;
        float v3 = i3 < end ? bhi(e3) : 0.f;
        acc[0] += v0 * blo(u0.x) + v1 * blo(u1.x);
        acc[1] += v0 * bhi(u0.x) + v1 * bhi(u1.x);
        acc[2] += v0 * blo(u0.y) + v1 * blo(u1.y);
        acc[3] += v0 * bhi(u0.y) + v1 * bhi(u1.y);
        acc[4] += v0 * blo(u0.z) + v1 * blo(u1.z);
        acc[5] += v0 * bhi(u0.z) + v1 * bhi(u1.z);
        acc[6] += v0 * blo(u0.w) + v1 * blo(u1.w);
        acc[7] += v0 * bhi(u0.w) + v1 * bhi(u1.w);
        acc[0] += v2 * blo(u2.x) + v3 * blo(u3.x);
        acc[1] += v2 * bhi(u2.x) + v3 * bhi(u3.x);
        acc[2] += v2 * blo(u2.y) + v3 * blo(u3.y);
        acc[3] += v2 * bhi(u2.y) + v3 * bhi(u3.y);
        acc[4] += v2 * blo(u2.z) + v3 * blo(u3.z);
        acc[5] += v2 * bhi(u2.z) + v3 * bhi(u3.z);
        acc[6] += v2 * blo(u2.w) + v3 * blo(u3.w);
        acc[7] += v2 * bhi(u2.w) + v3 * bhi(u3.w);
    }
    // combine the 4 quarters
    #pragma unroll
    for (int k = 0; k < 8; ++k) {
        acc[k] += __shfl_xor(acc[k], 16);
        acc[k] += __shfl_xor(acc[k], 32);
    }
    if (quarter != 0) return;

    if (post == 0) {
        uint4 s;
        s.x = (unsigned)bfr(acc[0]) | ((unsigned)bfr(acc[1]) << 16);
        s.y = (unsigned)bfr(acc[2]) | ((unsigned)bfr(acc[3]) << 16);
        s.z = (unsigned)bfr(acc[4]) | ((unsigned)bfr(acc[5]) << 16);
        s.w = (unsigned)bfr(acc[6]) | ((unsigned)bfr(acc[7]) << 16);
        ((uint4*)(out_bf + (size_t)row * HD))[q] = s;
        return;
    }
    if (post == 1) {
        #pragma unroll
        for (int k = 0; k < 8; ++k) acc[k] = acc[k] >= 0.f ? acc[k] : LEAKY * acc[k];
    }
    float t = 0.f;
    #pragma unroll
    for (int k = 0; k < 8; ++k) t += acc[k];
    #pragma unroll
    for (int off = 1; off < 16; off <<= 1) t += __shfl_xor(t, off);
    float mu = t * (1.f / HD);
    float d[8], vs = 0.f;
    #pragma unroll
    for (int k = 0; k < 8; ++k) { d[k] = acc[k] - mu; vs += d[k] * d[k]; }
    #pragma unroll
    for (int off = 1; off < 16; off <<= 1) vs += __shfl_xor(vs, off);
    float inv = rsqrtf(vs * (1.f / HD) + LN_EPS);

    float4 g0 = ((const float4*)gamma)[2 * q], g1 = ((const float4*)gamma)[2 * q + 1];
    float4 b0 = ((const float4*)beta)[2 * q],  b1 = ((const float4*)beta)[2 * q + 1];
    float4 r0 = ((const float4*)(res + (size_t)row * HD))[2 * q];
    float4 r1 = ((const float4*)(res + (size_t)row * HD))[2 * q + 1];
    float o[8];
    o[0] = d[0] * inv * g0.x + b0.x + r0.x;
    o[1] = d[1] * inv * g0.y + b0.y + r0.y;
    o[2] = d[2] * inv * g0.z + b0.z + r0.z;
    o[3] = d[3] * inv * g0.w + b0.w + r0.w;
    o[4] = d[4] * inv * g1.x + b1.x + r1.x;
    o[5] = d[5] * inv * g1.y + b1.y + r1.y;
    o[6] = d[6] * inv * g1.z + b1.z + r1.z;
    o[7] = d[7] * inv * g1.w + b1.w + r1.w;
    if (post == 1) {
        uint4 s;
        s.x = (unsigned)bfr(o[0]) | ((unsigned)bfr(o[1]) << 16);
        s.y = (unsigned)bfr(o[2]) | ((unsigned)bfr(o[3]) << 16);
        s.z = (unsigned)bfr(o[4]) | ((unsigned)bfr(o[5]) << 16);
        s.w = (unsigned)bfr(o[6]) | ((unsigned)bfr(o[7]) << 16);
        ((uint4*)(out_bf + (size_t)row * HD))[q] = s;
    } else {
        float4 s0 = {o[0], o[1], o[2], o[3]};
        float4 s1 = {o[4], o[5], o[6], o[7]};
        ((float4*)(out_f32 + (size_t)row * HD))[2 * q] = s0;
        ((float4*)(out_f32 + (size_t)row * HD))[2 * q + 1] = s1;
    }
}

extern "C" void kernel_launch(void* const* d_in, const int* in_sizes, int n_in,
                              void* d_out, int out_size, void* d_ws, size_t ws_size,
                              hipStream_t stream) {
    const float* ego   = (const float*)d_in[0];
    const float* vals  = (const float*)d_in[1];
    const float* gamma = (const float*)d_in[2];
    const float* beta  = (const float*)d_in[3];
    const int*   rows  = (const int*)d_in[4];
    const int*   cols  = (const int*)d_in[5];

    const int N   = in_sizes[0] / HD;   // 50000 (< 65536 for 16-bit node ids)
    const int NNZ = in_sizes[1];        // 800000
    const int NBK = (N + 255) >> 8;     // 196 buckets (<= 256)

    float* out = (float*)d_out;
    char* w = (char*)d_ws;
    unsigned short* ego_bf = (unsigned short*)w; w += (size_t)N * HD * 2;
    unsigned short* bufA   = (unsigned short*)w; w += (size_t)N * HD * 2;
    unsigned short* bufB   = (unsigned short*)w; w += (size_t)N * HD * 2;  // aliases stg
    int*  rp_r = (int*)w;  w += (size_t)(N + 4) * 4;
    int*  rp_c = (int*)w;  w += (size_t)(N + 4) * 4;
    unsigned* ent_r = (unsigned*)w; w += (size_t)NNZ * 4;
    unsigned* ent_c = (unsigned*)w; w += (size_t)NNZ * 4;
    int* counts = (int*)w; w += (size_t)2 * PB * NBA * 4;
    int* totals = (int*)w; w += (size_t)2 * NBA * 4;
    int* bases  = (int*)w; w += (size_t)2 * NBA * 4;

    // staging aliases bufB (2*NNZ*8 = 12.8 MB = bufB size; consumed by
    // bucket_build, which runs before spmm #2 writes bufB).
    uint2* stg_r = (uint2*)bufB;
    uint2* stg_c = stg_r + NNZ;

    // ---- build both CSRs + bf16 ego ----
    f32_to_bf16<<<(N * HD / 4 + 255) / 256, 256, 0, stream>>>(ego, ego_bf, N * HD / 4);
    part_count<<<PB, 256, 0, stream>>>(rows, cols, counts, NNZ);
    part_off<<<dim3(NBK, 2), 64, 0, stream>>>(counts, totals);
    base_scan<<<1, 128, 0, stream>>>(totals, bases, rp_r, rp_c, NBK, N, NNZ);
    part_scatter<<<PB, 256, 0, stream>>>(rows, cols, vals, counts, bases,
                                         stg_r, stg_c, NNZ);
    bucket_build<<<dim3(NBK, 2), 1024, 0, stream>>>(stg_r, stg_c, totals, bases,
                                                    ent_r, ent_c, rp_r, rp_c, N);

    const int sblocks = (N + 3) / 4;

    // ---- layer 0 ----
    spmm_bf<<<sblocks, 256, 0, stream>>>(ego_bf, rp_c, ent_c,
                                         nullptr, nullptr, nullptr, bufA, nullptr, N, 0);
    spmm_bf<<<sblocks, 256, 0, stream>>>(bufA, rp_r, ent_r,
                                         ego, gamma, beta, bufB, nullptr, N, 1);
    // ---- layer 1 ----
    spmm_bf<<<sblocks, 256, 0, stream>>>(bufB, rp_c, ent_c,
                                         nullptr, nullptr, nullptr, bufA, nullptr, N, 0);
    spmm_bf<<<sblocks, 256, 0, stream>>>(bufA, rp_r, ent_r,
                                         ego, gamma + HD, beta + HD, nullptr, out, N, 2);
}